// Round 17
// baseline (410.674 us; speedup 1.0000x reference)
//
#include <hip/hip_runtime.h>
#include <hip/hip_bf16.h>
#include <hip/hip_fp8.h>
#include <stdint.h>

#define DIMS 1024
#define STATE 2048
#define BATCH 4
#define SEQ 2048
#define TOKENS 8192   // BATCH*SEQ
#define N1 8192       // fused GEMM1 output columns, INTERLEAVED: col = ch*4 + stream
#define NCHUNK 16
#define CHUNKL (SEQ / NCHUNK)   // 128

typedef __hip_bfloat16 bf16;
typedef unsigned char u8;
typedef unsigned short u16;
typedef __attribute__((ext_vector_type(4))) float f32x4;
typedef __attribute__((ext_vector_type(16))) float f32x16;
typedef __attribute__((ext_vector_type(2))) long v2i64;
typedef __attribute__((ext_vector_type(4))) int v4i;
typedef __attribute__((ext_vector_type(8))) int v8i;

// static fp8 scales: GEMM1 xn*32, W1*256; GEMM2 sco*32, W2*256 -> acc/8192
#define XN_SCALE 32.0f
#define W1_SCALE 256.0f
#define H_SCALE  32.0f
#define W2_SCALE 256.0f
#define INV_SCALE (1.0f / 8192.0f)

__device__ __forceinline__ float sigmoidf_(float x) {
  return 1.0f / (1.0f + __expf(-x));
}

__device__ __forceinline__ u8 to_fp8(float f) {
  __hip_fp8_e4m3 h(f);
  return h.__x;
}

// exact bf16(bits)->f32
__device__ __forceinline__ float b2f(u16 v) {
  union { uint32_t u; float f; } w;
  w.u = ((uint32_t)v) << 16;
  return w.f;
}

__device__ __forceinline__ u16 f2b(float f) {
  bf16 h = __float2bfloat16(f);
  return *(u16*)&h;
}

// async global->LDS, 16B per lane. LDS dest must be wave-uniform base; HW does base + lane*16.
__device__ __forceinline__ void async_copy16(const void* g, void* l) {
  __builtin_amdgcn_global_load_lds(
      (const __attribute__((address_space(1))) void*)(uintptr_t)g,
      (__attribute__((address_space(3))) void*)(uint32_t)(uintptr_t)l,
      16, 0, 0);
}

// ---- LDS XOR swizzle for 64 B rows (4 x 16B chunks): bank period = row pair ----
__device__ __forceinline__ int swz32(int row, int kc) {
  int line = row >> 1;
  int sub = ((row & 1) << 2) | kc;
  return (line << 3) | (sub ^ (line & 7));
}
__device__ __forceinline__ void swz32_dec(int c, int& row, int& kc) {
  int line = c >> 3;
  int sub = (c & 7) ^ (line & 7);
  row = (line << 1) | (sub >> 2);
  kc = sub & 3;
}

// ---- bijective XCD-chunked block swizzle (T1): requires nwg % 8 == 0 ----
__device__ __forceinline__ int xcd_swz(int wg, int nwg) {
  return (wg & 7) * (nwg >> 3) + (wg >> 3);
}

// ---------------- weight transpose + fp32->fp8 cast ----------------
// W[K][N] -> Wt[perm(N)][K] fp8 e4m3 * scale, PLAIN k-order (both GEMMs are
// MX: each lane reads 32 contiguous k-bytes).
// interleave=1 (W1): fused col n -> dst row = ch*4 + (stream_base + n>>11).
__global__ __launch_bounds__(256) void transpose_fp8_kernel(
    const float* __restrict__ W, u8* __restrict__ Wt, int K, int N,
    int stream_base, int interleave, float scale) {
  __shared__ float tile[32][33];
  int tx = threadIdx.x & 31;
  int ty = threadIdx.x >> 5;
  long col = (long)blockIdx.x * 32 + tx;
  long rowb = (long)blockIdx.y * 32;
#pragma unroll
  for (int i = 0; i < 32; i += 8)
    tile[ty + i][tx] = W[(rowb + ty + i) * N + col];
  __syncthreads();
  long ocol = rowb + tx;
  long orow = (long)blockIdx.x * 32 + ty;  // original output-channel index
#pragma unroll
  for (int i = 0; i < 32; i += 8) {
    long n = orow + i;
    long dstrow = interleave ? (((n & 2047) << 2) | (stream_base + (n >> 11))) : n;
    Wt[dstrow * K + ocol] = to_fp8(tile[tx][ty + i] * scale);
  }
}

// ---------------- split RMSNorm -> fp8 (plain k-order, *XN_SCALE) ------------
__global__ __launch_bounds__(256) void rmsnorm_kernel(
    const float* __restrict__ x, const float* __restrict__ ls,
    const float* __restrict__ rs, const float* __restrict__ ss,
    u8* __restrict__ xn8) {
  int token = blockIdx.x;
  int tid = threadIdx.x;  // 256 threads, 4 floats each
  const float4* xt = (const float4*)(x + (long)token * DIMS);
  float4 v = xt[tid];
  float s = v.x * v.x + v.y * v.y + v.z * v.z + v.w * v.w;
#pragma unroll
  for (int d = 32; d > 0; d >>= 1) s += __shfl_down(s, d);
  __shared__ float parts[4];
  if ((tid & 63) == 0) parts[tid >> 6] = s;
  __syncthreads();
  int j = tid * 4;
  bool left = j < 512;
  float sum = left ? (parts[0] + parts[1]) : (parts[2] + parts[3]);
  float n = sqrtf(sum * (1.0f / 512.0f));  // ||v||*d^-1/2
  float inv = 1.0f / (n + 1e-8f);
  const float4* sc = (const float4*)(left ? ls : rs);
  float4 g = sc[left ? tid : tid - 128];
  float4 p = ((const float4*)ss)[tid];
  u8 q[4];
  q[0] = to_fp8(v.x * g.x * inv * p.x * XN_SCALE);
  q[1] = to_fp8(v.y * g.y * inv * p.y * XN_SCALE);
  q[2] = to_fp8(v.z * g.z * inv * p.z * XN_SCALE);
  q[3] = to_fp8(v.w * g.w * inv * p.w * XN_SCALE);
  *(uint32_t*)(xn8 + (long)token * DIMS + j) = *(uint32_t*)q;
}

__device__ __forceinline__ v8i ld_frag64(const u8* base, int row, int q4) {
  // lane's 32 contiguous k-bytes = swizzled chunks 2*q4, 2*q4+1 of the row
  v4i lo = *(const v4i*)(base + swz32(row, q4 * 2) * 16);
  v4i hi = *(const v4i*)(base + swz32(row, q4 * 2 + 1) * 16);
  return __builtin_shufflevector(lo, hi, 0, 1, 2, 3, 4, 5, 6, 7);
}

// ---------------- GEMM1 MX-fp8: 256x128 block, BK=64, 3-buf vmcnt (R19) ------
// MX core from R15 (measured 161us) + R3's 3-buffer counted-vmcnt shell
// (measured 183 vs 190 for drain-to-zero on the SAME non-MX arithmetic --
// the only shell that beat drain in this session). Loads stay in flight
// across the barrier: vmcnt(6) leaves the newest stage's 6 copies pending.
// 72 KB LDS -> still 2 resident blocks/CU (144 <= 160; R13: 3 thrashes L2).
__device__ __forceinline__ void g1f8_stage(const u8* __restrict__ A,
                                           const u8* __restrict__ Bt,
                                           long arow0, long brow0, int k0,
                                           int wave, int lane, u8* As, u8* Bs) {
  const int K = DIMS;
#pragma unroll
  for (int i = 0; i < 4; i++) {  // A: 1024 chunks (256 rows x 4)
    int c = (wave * 4 + i) * 64 + lane;
    int row, kc; swz32_dec(c, row, kc);
    async_copy16(A + (arow0 + row) * K + k0 + kc * 16, (char*)As + (wave * 4 + i) * 1024);
  }
#pragma unroll
  for (int i = 0; i < 2; i++) {  // B: 512 chunks (128 rows x 4)
    int c = (wave * 2 + i) * 64 + lane;
    int row, kc; swz32_dec(c, row, kc);
    async_copy16(Bt + (brow0 + row) * K + k0 + kc * 16, (char*)Bs + (wave * 2 + i) * 1024);
  }
}

__global__ __launch_bounds__(256, 2) void gemm1_fp8(
    const u8* __restrict__ A, const u8* __restrict__ Bt,
    uint32_t* __restrict__ AU, u16* __restrict__ GO) {
  __shared__ __align__(16) u8 As[3][256 * 64];  // 3 x 16 KB
  __shared__ __align__(16) u8 Bs[3][128 * 64];  // 3 x 8 KB  -> 72 KB total
  int tid = threadIdx.x;
  int lane = tid & 63, wave = tid >> 6;
  int wm = wave & 1, wn = wave >> 1;
  // T1: bijective XCD swizzle over the 2048-block grid (row-major wg).
  int wg = xcd_swz(blockIdx.y * gridDim.x + blockIdx.x, gridDim.x * gridDim.y);
  int bx = wg & 63;      // gridDim.x = 64
  int by = wg >> 6;
  long arow0 = (long)by * 256;
  long brow0 = (long)bx * 128;
  int m_lane = lane & 31, q4 = lane >> 5;
  f32x16 acc[4][2] = {};

  // prologue: 2 tiles in flight (12 copies/thread outstanding)
  g1f8_stage(A, Bt, arow0, brow0, 0, wave, lane, As[0], Bs[0]);
  g1f8_stage(A, Bt, arow0, brow0, 64, wave, lane, As[1], Bs[1]);

  int cur = 0, nxt = 2;
  for (int it = 0; it < 16; ++it) {
    // RAW: own stage(it) landed (6 newer copies may remain); barrier then
    // guarantees all waves' stage(it) landed. Tail drains fully.
    if (it == 15) asm volatile("s_waitcnt vmcnt(0)" ::: "memory");
    else          asm volatile("s_waitcnt vmcnt(6)" ::: "memory");
    __builtin_amdgcn_s_barrier();
    __builtin_amdgcn_sched_barrier(0);
    // WAR: buf[nxt] = buf[(it-1)%3]; all waves consumed it-1 before barrier it.
    if (it + 2 < 16)
      g1f8_stage(A, Bt, arow0, brow0, (it + 2) * 64, wave, lane, As[nxt], Bs[nxt]);
    const u8* Asc = As[cur];
    const u8* Bsc = Bs[cur];
    v8i af[4], bf[2];
#pragma unroll
    for (int mt = 0; mt < 4; mt++)
      af[mt] = ld_frag64(Asc, wm * 128 + mt * 32 + m_lane, q4);
#pragma unroll
    for (int nt = 0; nt < 2; nt++)
      bf[nt] = ld_frag64(Bsc, wn * 64 + nt * 32 + m_lane, q4);
    __builtin_amdgcn_s_setprio(1);
#pragma unroll
    for (int mt = 0; mt < 4; mt++)
#pragma unroll
      for (int nt = 0; nt < 2; nt++)
        acc[mt][nt] = __builtin_amdgcn_mfma_scale_f32_32x32x64_f8f6f4(
            bf[nt], af[mt], acc[mt][nt], 0, 0, /*opsel_a*/0, /*scale_a*/127,
            /*opsel_b*/0, /*scale_b*/127);
    __builtin_amdgcn_s_setprio(0);
    cur = cur == 2 ? 0 : cur + 1;
    nxt = nxt == 2 ? 0 : nxt + 1;
  }

  // Epilogue: quad g (cols ch*4 .. ch*4+3) = {Kraw, uraw, gin, gout} of one
  // channel. Compute activations in f32, store AU (4B) + GO (2B).
#pragma unroll
  for (int mt = 0; mt < 4; mt++) {
    long row = arow0 + wm * 128 + mt * 32 + m_lane;  // token
    long rb = row * STATE;
#pragma unroll
    for (int nt = 0; nt < 2; nt++) {
#pragma unroll
      for (int g = 0; g < 4; g++) {
        long col = brow0 + wn * 64 + nt * 32 + g * 8 + q4 * 4;  // interleaved col
        long ch = col >> 2;
        float kraw = acc[mt][nt][g * 4 + 0] * INV_SCALE;
        float uraw = acc[mt][nt][g * 4 + 1] * INV_SCALE;
        float gin  = acc[mt][nt][g * 4 + 2] * INV_SCALE;
        float gout = acc[mt][nt][g * 4 + 3] * INV_SCALE;
        float ah = sigmoidf_(kraw);                     // a-hat_t = sigma(K_t)
        float uu = uraw * sigmoidf_(gin) * (1.0f - ah); // u_t
        u16 pr[2];
        pr[0] = f2b(ah);  // low 16 bits
        pr[1] = f2b(uu);  // high 16 bits
        AU[rb + ch] = *(uint32_t*)pr;
        GO[rb + ch] = f2b(sigmoidf_(gout));
      }
    }
  }
}

// ---------------- GEMM2 MX-fp8: 128x128 block, BK=128 (R17, measured) --------
// 2-buffer 64 KB, 16 iterations; vrow = row*2 + khalf layout.
__device__ __forceinline__ void g2f8_stage(const u8* __restrict__ A,
                                           const u8* __restrict__ Bt,
                                           long arow0, long brow0, int k0,
                                           int wave, int lane, u8* As, u8* Bs) {
  const int K = STATE;
#pragma unroll
  for (int i = 0; i < 4; i++) {  // A: 1024 chunks (256 vrows x 4)
    int c = (wave * 4 + i) * 64 + lane;
    int vrow, kc; swz32_dec(c, vrow, kc);
    async_copy16(A + (arow0 + (vrow >> 1)) * K + k0 + (vrow & 1) * 64 + kc * 16,
                 (char*)As + (wave * 4 + i) * 1024);
  }
#pragma unroll
  for (int i = 0; i < 4; i++) {  // B: 1024 chunks (256 vrows x 4)
    int c = (wave * 4 + i) * 64 + lane;
    int vrow, kc; swz32_dec(c, vrow, kc);
    async_copy16(Bt + (brow0 + (vrow >> 1)) * K + k0 + (vrow & 1) * 64 + kc * 16,
                 (char*)Bs + (wave * 4 + i) * 1024);
  }
}

__global__ __launch_bounds__(256, 2) void gemm2_fp8(
    const u8* __restrict__ A, const u8* __restrict__ Bt,
    float* __restrict__ C, const float* __restrict__ resid) {
  __shared__ __align__(16) u8 As0[128 * 128], As1[128 * 128];  // 16 KB each
  __shared__ __align__(16) u8 Bs0[128 * 128], Bs1[128 * 128];  // 16 KB each -> 64 KB
  int tid = threadIdx.x;
  int lane = tid & 63, wave = tid >> 6;
  int wm = wave & 1, wn = wave >> 1;
  // T1: bijective XCD swizzle over the 512-block grid (row-major wg).
  int wg = xcd_swz(blockIdx.y * gridDim.x + blockIdx.x, gridDim.x * gridDim.y);
  int bx = wg & (gridDim.x - 1);          // gridDim.x = 8 (pow2)
  int by = wg >> 3;
  long arow0 = (long)by * 128;
  long brow0 = (long)bx * 128;
  int m_lane = lane & 31, q4 = lane >> 5;
  f32x16 acc[2][2] = {};

  g2f8_stage(A, Bt, arow0, brow0, 0, wave, lane, As0, Bs0);
  __syncthreads();  // cold fill, once

  for (int it = 0; it < 16; ++it) {
    const u8* Asc = (it & 1) ? As1 : As0;
    const u8* Bsc = (it & 1) ? Bs1 : Bs0;
    u8* Asn = (it & 1) ? As0 : As1;
    u8* Bsn = (it & 1) ? Bs0 : Bs1;
    if (it + 1 < 16)
      g2f8_stage(A, Bt, arow0, brow0, (it + 1) * 128, wave, lane, Asn, Bsn);
#pragma unroll
    for (int ks = 0; ks < 2; ks++) {  // two 64-k halves of the 128-k tile
      v8i af[2], bf[2];
#pragma unroll
      for (int mt = 0; mt < 2; mt++)
        af[mt] = ld_frag64(Asc, (wm * 64 + mt * 32 + m_lane) * 2 + ks, q4);
#pragma unroll
      for (int nt = 0; nt < 2; nt++)
        bf[nt] = ld_frag64(Bsc, (wn * 64 + nt * 32 + m_lane) * 2 + ks, q4);
#pragma unroll
      for (int mt = 0; mt < 2; mt++)
#pragma unroll
        for (int nt = 0; nt < 2; nt++)
          acc[mt][nt] = __builtin_amdgcn_mfma_scale_f32_32x32x64_f8f6f4(
              bf[nt], af[mt], acc[mt][nt], 0, 0, 0, 127, 0, 127);
    }
    __syncthreads();
  }
  // token = arow0 + wm*64 + mt*32 + m_lane; ycol = brow0 + wn*64 + nt*32 + g*8 + q4*4 + j
#pragma unroll
  for (int mt = 0; mt < 2; mt++) {
    long row = arow0 + wm * 64 + mt * 32 + m_lane;
#pragma unroll
    for (int nt = 0; nt < 2; nt++) {
#pragma unroll
      for (int g = 0; g < 4; g++) {
        long col = brow0 + wn * 64 + nt * 32 + g * 8 + q4 * 4;
        float4 rv = *(const float4*)(resid + row * DIMS + col);
        float4 ov;
        ov.x = acc[mt][nt][g * 4 + 0] * INV_SCALE + rv.x;
        ov.y = acc[mt][nt][g * 4 + 1] * INV_SCALE + rv.y;
        ov.z = acc[mt][nt][g * 4 + 2] * INV_SCALE + rv.z;
        ov.w = acc[mt][nt][g * 4 + 3] * INV_SCALE + rv.w;
        *(float4*)(C + row * DIMS + col) = ov;
      }
    }
  }
}

// ---------------- chunked gated linear scan (AU/GO inputs) -------------------
// AU[t][ch] = {a-hat_t = sigma(K_t), u_t} 2xbf16; GO[t][ch] = sigma(g_out) bf16.
// Recurrence: h_t = a_t h_{t-1} + u_t with a_t = a-hat_{t-1} (shift handled
// here), a_0 = 1.
__global__ __launch_bounds__(256) void chunk_summary_kernel(
    const uint32_t* __restrict__ AU, float* __restrict__ carryA,
    float* __restrict__ carryU) {
  int b = blockIdx.x;
  int ch = blockIdx.y * 256 + threadIdx.x;
  int chunk = blockIdx.z;
  int t0 = chunk * CHUNKL;
  const uint32_t* base = AU + (long)b * SEQ * STATE + ch;
  // ap = a-hat_{t-1} entering token t; boundary from previous chunk's last token.
  float ap = 1.0f;
  if (chunk != 0) ap = b2f((u16)(base[(long)(t0 - 1) * STATE] & 0xffff));
  float A = 1.0f, U = 0.0f;
#pragma unroll 8
  for (int t = t0; t < t0 + CHUNKL; t++) {
    uint32_t w = base[(long)t * STATE];
    float ah = b2f((u16)(w & 0xffff));
    float u  = b2f((u16)(w >> 16));
    A *= ap;
    U = ap * U + u;
    ap = ah;
  }
  int cidx = (b * NCHUNK + chunk) * STATE + ch;
  carryA[cidx] = A;
  carryU[cidx] = U;
}

// Pass C (R19: carry_scan FUSED): each block computes its chunk's carry-in by
// the <=15-step serial recurrence over carryA/carryU (wave-uniform broadcast
// loads) -- removes the carry_scan launch + carryIn round-trip.
// Writes h*sigma(g_out) as fp8*H_SCALE, PLAIN k-order (gemm2 is MX).
__global__ __launch_bounds__(256) void scan_chunk_kernel(
    const uint32_t* __restrict__ AU, const u16* __restrict__ GO,
    const float* __restrict__ carryA, const float* __restrict__ carryU,
    u8* __restrict__ sco8) {
  int b = blockIdx.x;
  int c0 = blockIdx.y * 32;
  int chunk = blockIdx.z;
  int tstart = chunk * CHUNKL;
  __shared__ float a_s[32][65], u_s[32][65], h_s[32][65];
  int tid = threadIdx.x;
  int lane = tid & 63, wave = tid >> 6;
  int cc = tid & 31;
  int tq = tid >> 5;

  float carryH[8], carryK[8];
#pragma unroll
  for (int i = 0; i < 8; i++) {
    int ch = c0 + wave * 8 + i;
    // carry-in = scan of per-chunk summaries over chunks < chunk
    float h = 0.0f;
    for (int c = 0; c < chunk; c++) {
      int cidx = (b * NCHUNK + c) * STATE + ch;
      h = carryA[cidx] * h + carryU[cidx];
    }
    carryH[i] = h;
    carryK[i] = (chunk == 0)
                    ? 1.0f
                    : b2f((u16)(AU[((long)(b * SEQ + tstart - 1)) * STATE + ch] & 0xffff));
  }

  float g_r[8];
  for (int t0 = tstart; t0 < tstart + CHUNKL; t0 += 64) {
#pragma unroll
    for (int i = 0; i < 8; i++) {
      int t = tq * 8 + i;
      long idx = ((long)(b * SEQ + t0 + t)) * STATE + c0 + cc;
      uint32_t w = AU[idx];
      a_s[cc][t] = b2f((u16)(w & 0xffff));  // a-hat_t
      u_s[cc][t] = b2f((u16)(w >> 16));     // u_t
      g_r[i] = b2f(GO[idx]);
    }
    __syncthreads();
#pragma unroll
    for (int i = 0; i < 8; i++) {
      int ch = wave * 8 + i;
      float aK = a_s[ch][lane];
      float u = u_s[ch][lane];
      float a = __shfl_up(aK, 1);   // a_t = a-hat_{t-1}
      if (lane == 0) a = carryK[i];
      float A = a, U = u;
#pragma unroll
      for (int d = 1; d < 64; d <<= 1) {
        float Au = __shfl_up(A, d);
        float Uu = __shfl_up(U, d);
        if (lane >= d) { U += A * Uu; A *= Au; }
      }
      float h = U + A * carryH[i];
      carryH[i] = __shfl(h, 63);
      carryK[i] = __shfl(aK, 63);
      h_s[ch][lane] = h;
    }
    __syncthreads();
#pragma unroll
    for (int i = 0; i < 8; i++) {
      int t = tq * 8 + i;
      sco8[((long)(b * SEQ + t0 + t)) * STATE + c0 + cc] =
          to_fp8(h_s[cc][t] * g_r[i] * H_SCALE);
    }
    __syncthreads();
  }
}

extern "C" void kernel_launch(void* const* d_in, const int* in_sizes, int n_in,
                              void* d_out, int out_size, void* d_ws, size_t ws_size,
                              hipStream_t stream) {
  const float* x    = (const float*)d_in[0];
  const float* ls   = (const float*)d_in[1];
  const float* rs   = (const float*)d_in[2];
  const float* ss   = (const float*)d_in[3];
  const float* Wk   = (const float*)d_in[4];
  const float* Wugg = (const float*)d_in[5];
  const float* Wout = (const float*)d_in[6];
  float* out = (float*)d_out;

  // workspace layout (~130 MB)
  char* ws = (char*)d_ws;
  u8*   W1f8 = (u8*)ws;                                  // [8192][1024] fp8 = 8 MB (interleaved)
  u8*   W2f8 = (u8*)(ws + 8388608);                      // [1024][2048] fp8 = 2 MB
  u8*   xn8  = (u8*)(ws + 10485760);                     // [8192][1024] fp8 = 8 MB
  uint32_t* AU = (uint32_t*)(ws + 18874368);             // [8192][2048] 2xbf16 = 64 MB
  u16*  GOb  = (u16*)(ws + 18874368 + 67108864);         // [8192][2048] bf16 = 32 MB
  u8*   sco8 = (u8*)(ws + 18874368 + 67108864 + 33554432); // [8192][2048] fp8 = 16.7 MB
  // carry buffers (2 x 512 KB) overlay xn8: xn8 is dead after gemm1.
  float* carryA  = (float*)xn8;
  float* carryU  = carryA + BATCH * NCHUNK * STATE;

  // W1 -> fp8 (scaled, PLAIN k-order, channel-interleaved rows);
  // W2 -> fp8 (PLAIN k-order rows) -- both GEMMs are MX.
  transpose_fp8_kernel<<<dim3(STATE / 32, DIMS / 32), 256, 0, stream>>>(
      Wk, W1f8, DIMS, STATE, 0, 1, W1_SCALE);
  transpose_fp8_kernel<<<dim3(3 * STATE / 32, DIMS / 32), 256, 0, stream>>>(
      Wugg, W1f8, DIMS, 3 * STATE, 1, 1, W1_SCALE);
  transpose_fp8_kernel<<<dim3(DIMS / 32, STATE / 32), 256, 0, stream>>>(
      Wout, W2f8, STATE, DIMS, 0, 0, W2_SCALE);

  rmsnorm_kernel<<<TOKENS, 256, 0, stream>>>(x, ls, rs, ss, xn8);

  gemm1_fp8<<<dim3(N1 / 128, TOKENS / 256), 256, 0, stream>>>(xn8, W1f8, AU, GOb);

  chunk_summary_kernel<<<dim3(BATCH, STATE / 256, NCHUNK), 256, 0, stream>>>(
      AU, carryA, carryU);
  scan_chunk_kernel<<<dim3(BATCH, STATE / 32, NCHUNK), 256, 0, stream>>>(
      AU, GOb, carryA, carryU, sco8);

  gemm2_fp8<<<dim3(DIMS / 128, TOKENS / 128), 256, 0, stream>>>(
      sco8, W2f8, out, x);
}

// Round 18
// 368.741 us; speedup vs baseline: 1.1137x; 1.1137x over previous
//
#include <hip/hip_runtime.h>
#include <hip/hip_bf16.h>
#include <hip/hip_fp8.h>
#include <stdint.h>

#define DIMS 1024
#define STATE 2048
#define BATCH 4
#define SEQ 2048
#define TOKENS 8192   // BATCH*SEQ
#define N1 8192       // fused GEMM1 output columns, INTERLEAVED: col = ch*4 + stream
#define NCHUNK 16
#define CHUNKL (SEQ / NCHUNK)   // 128

typedef __hip_bfloat16 bf16;
typedef unsigned char u8;
typedef unsigned short u16;
typedef __attribute__((ext_vector_type(4))) float f32x4;
typedef __attribute__((ext_vector_type(16))) float f32x16;
typedef __attribute__((ext_vector_type(2))) long v2i64;
typedef __attribute__((ext_vector_type(4))) int v4i;
typedef __attribute__((ext_vector_type(8))) int v8i;

// static fp8 scales: GEMM1 xn*32, W1*256; GEMM2 sco*32, W2*256 -> acc/8192
#define XN_SCALE 32.0f
#define W1_SCALE 256.0f
#define H_SCALE  32.0f
#define W2_SCALE 256.0f
#define INV_SCALE (1.0f / 8192.0f)

__device__ __forceinline__ float sigmoidf_(float x) {
  return 1.0f / (1.0f + __expf(-x));
}

__device__ __forceinline__ u8 to_fp8(float f) {
  __hip_fp8_e4m3 h(f);
  return h.__x;
}

// exact bf16(bits)->f32
__device__ __forceinline__ float b2f(u16 v) {
  union { uint32_t u; float f; } w;
  w.u = ((uint32_t)v) << 16;
  return w.f;
}

__device__ __forceinline__ u16 f2b(float f) {
  bf16 h = __float2bfloat16(f);
  return *(u16*)&h;
}

// async global->LDS, 16B per lane. LDS dest must be wave-uniform base; HW does base + lane*16.
__device__ __forceinline__ void async_copy16(const void* g, void* l) {
  __builtin_amdgcn_global_load_lds(
      (const __attribute__((address_space(1))) void*)(uintptr_t)g,
      (__attribute__((address_space(3))) void*)(uint32_t)(uintptr_t)l,
      16, 0, 0);
}

// ---- LDS XOR swizzle for 64 B rows (4 x 16B chunks): bank period = row pair ----
__device__ __forceinline__ int swz32(int row, int kc) {
  int line = row >> 1;
  int sub = ((row & 1) << 2) | kc;
  return (line << 3) | (sub ^ (line & 7));
}
__device__ __forceinline__ void swz32_dec(int c, int& row, int& kc) {
  int line = c >> 3;
  int sub = (c & 7) ^ (line & 7);
  row = (line << 1) | (sub >> 2);
  kc = sub & 3;
}

// ---- bijective XCD-chunked block swizzle (T1): requires nwg % 8 == 0 ----
__device__ __forceinline__ int xcd_swz(int wg, int nwg) {
  return (wg & 7) * (nwg >> 3) + (wg >> 3);
}

// ---------------- weight transpose + fp32->fp8 cast ----------------
// W[K][N] -> Wt[perm(N)][K] fp8 e4m3 * scale, PLAIN k-order (both GEMMs are
// MX: each lane reads 32 contiguous k-bytes).
// interleave=1 (W1): fused col n -> dst row = ch*4 + (stream_base + n>>11).
__global__ __launch_bounds__(256) void transpose_fp8_kernel(
    const float* __restrict__ W, u8* __restrict__ Wt, int K, int N,
    int stream_base, int interleave, float scale) {
  __shared__ float tile[32][33];
  int tx = threadIdx.x & 31;
  int ty = threadIdx.x >> 5;
  long col = (long)blockIdx.x * 32 + tx;
  long rowb = (long)blockIdx.y * 32;
#pragma unroll
  for (int i = 0; i < 32; i += 8)
    tile[ty + i][tx] = W[(rowb + ty + i) * N + col];
  __syncthreads();
  long ocol = rowb + tx;
  long orow = (long)blockIdx.x * 32 + ty;  // original output-channel index
#pragma unroll
  for (int i = 0; i < 32; i += 8) {
    long n = orow + i;
    long dstrow = interleave ? (((n & 2047) << 2) | (stream_base + (n >> 11))) : n;
    Wt[dstrow * K + ocol] = to_fp8(tile[tx][ty + i] * scale);
  }
}

// ---------------- split RMSNorm -> fp8 (plain k-order, *XN_SCALE) ------------
__global__ __launch_bounds__(256) void rmsnorm_kernel(
    const float* __restrict__ x, const float* __restrict__ ls,
    const float* __restrict__ rs, const float* __restrict__ ss,
    u8* __restrict__ xn8) {
  int token = blockIdx.x;
  int tid = threadIdx.x;  // 256 threads, 4 floats each
  const float4* xt = (const float4*)(x + (long)token * DIMS);
  float4 v = xt[tid];
  float s = v.x * v.x + v.y * v.y + v.z * v.z + v.w * v.w;
#pragma unroll
  for (int d = 32; d > 0; d >>= 1) s += __shfl_down(s, d);
  __shared__ float parts[4];
  if ((tid & 63) == 0) parts[tid >> 6] = s;
  __syncthreads();
  int j = tid * 4;
  bool left = j < 512;
  float sum = left ? (parts[0] + parts[1]) : (parts[2] + parts[3]);
  float n = sqrtf(sum * (1.0f / 512.0f));  // ||v||*d^-1/2
  float inv = 1.0f / (n + 1e-8f);
  const float4* sc = (const float4*)(left ? ls : rs);
  float4 g = sc[left ? tid : tid - 128];
  float4 p = ((const float4*)ss)[tid];
  u8 q[4];
  q[0] = to_fp8(v.x * g.x * inv * p.x * XN_SCALE);
  q[1] = to_fp8(v.y * g.y * inv * p.y * XN_SCALE);
  q[2] = to_fp8(v.z * g.z * inv * p.z * XN_SCALE);
  q[3] = to_fp8(v.w * g.w * inv * p.w * XN_SCALE);
  *(uint32_t*)(xn8 + (long)token * DIMS + j) = *(uint32_t*)q;
}

__device__ __forceinline__ v8i ld_frag64(const u8* base, int row, int q4) {
  // lane's 32 contiguous k-bytes = swizzled chunks 2*q4, 2*q4+1 of the row
  v4i lo = *(const v4i*)(base + swz32(row, q4 * 2) * 16);
  v4i hi = *(const v4i*)(base + swz32(row, q4 * 2 + 1) * 16);
  return __builtin_shufflevector(lo, hi, 0, 1, 2, 3, 4, 5, 6, 7);
}

// ---------------- GEMM1 MX-fp8: 256x128 block, BK=64, 3-buf vmcnt (R19) ------
// MEASURED 155.5us (R19 profile; beat the 2-buffer drain form's 161us).
// MX core (R15) + R3's 3-buffer counted-vmcnt shell: loads stay in flight
// across the barrier (vmcnt(6)). 72 KB LDS -> 2 resident blocks/CU.
__device__ __forceinline__ void g1f8_stage(const u8* __restrict__ A,
                                           const u8* __restrict__ Bt,
                                           long arow0, long brow0, int k0,
                                           int wave, int lane, u8* As, u8* Bs) {
  const int K = DIMS;
#pragma unroll
  for (int i = 0; i < 4; i++) {  // A: 1024 chunks (256 rows x 4)
    int c = (wave * 4 + i) * 64 + lane;
    int row, kc; swz32_dec(c, row, kc);
    async_copy16(A + (arow0 + row) * K + k0 + kc * 16, (char*)As + (wave * 4 + i) * 1024);
  }
#pragma unroll
  for (int i = 0; i < 2; i++) {  // B: 512 chunks (128 rows x 4)
    int c = (wave * 2 + i) * 64 + lane;
    int row, kc; swz32_dec(c, row, kc);
    async_copy16(Bt + (brow0 + row) * K + k0 + kc * 16, (char*)Bs + (wave * 2 + i) * 1024);
  }
}

__global__ __launch_bounds__(256, 2) void gemm1_fp8(
    const u8* __restrict__ A, const u8* __restrict__ Bt,
    uint32_t* __restrict__ AU, u16* __restrict__ GO) {
  __shared__ __align__(16) u8 As[3][256 * 64];  // 3 x 16 KB
  __shared__ __align__(16) u8 Bs[3][128 * 64];  // 3 x 8 KB  -> 72 KB total
  int tid = threadIdx.x;
  int lane = tid & 63, wave = tid >> 6;
  int wm = wave & 1, wn = wave >> 1;
  // T1: bijective XCD swizzle over the 2048-block grid (row-major wg).
  int wg = xcd_swz(blockIdx.y * gridDim.x + blockIdx.x, gridDim.x * gridDim.y);
  int bx = wg & 63;      // gridDim.x = 64
  int by = wg >> 6;
  long arow0 = (long)by * 256;
  long brow0 = (long)bx * 128;
  int m_lane = lane & 31, q4 = lane >> 5;
  f32x16 acc[4][2] = {};

  // prologue: 2 tiles in flight (12 copies/thread outstanding)
  g1f8_stage(A, Bt, arow0, brow0, 0, wave, lane, As[0], Bs[0]);
  g1f8_stage(A, Bt, arow0, brow0, 64, wave, lane, As[1], Bs[1]);

  int cur = 0, nxt = 2;
  for (int it = 0; it < 16; ++it) {
    // RAW: own stage(it) landed (6 newer copies may remain); barrier then
    // guarantees all waves' stage(it) landed. Tail drains fully.
    if (it == 15) asm volatile("s_waitcnt vmcnt(0)" ::: "memory");
    else          asm volatile("s_waitcnt vmcnt(6)" ::: "memory");
    __builtin_amdgcn_s_barrier();
    __builtin_amdgcn_sched_barrier(0);
    // WAR: buf[nxt] = buf[(it-1)%3]; all waves consumed it-1 before barrier it.
    if (it + 2 < 16)
      g1f8_stage(A, Bt, arow0, brow0, (it + 2) * 64, wave, lane, As[nxt], Bs[nxt]);
    const u8* Asc = As[cur];
    const u8* Bsc = Bs[cur];
    v8i af[4], bf[2];
#pragma unroll
    for (int mt = 0; mt < 4; mt++)
      af[mt] = ld_frag64(Asc, wm * 128 + mt * 32 + m_lane, q4);
#pragma unroll
    for (int nt = 0; nt < 2; nt++)
      bf[nt] = ld_frag64(Bsc, wn * 64 + nt * 32 + m_lane, q4);
    __builtin_amdgcn_s_setprio(1);
#pragma unroll
    for (int mt = 0; mt < 4; mt++)
#pragma unroll
      for (int nt = 0; nt < 2; nt++)
        acc[mt][nt] = __builtin_amdgcn_mfma_scale_f32_32x32x64_f8f6f4(
            bf[nt], af[mt], acc[mt][nt], 0, 0, /*opsel_a*/0, /*scale_a*/127,
            /*opsel_b*/0, /*scale_b*/127);
    __builtin_amdgcn_s_setprio(0);
    cur = cur == 2 ? 0 : cur + 1;
    nxt = nxt == 2 ? 0 : nxt + 1;
  }

  // Epilogue: quad g (cols ch*4 .. ch*4+3) = {Kraw, uraw, gin, gout} of one
  // channel. Compute activations in f32, store AU (4B) + GO (2B).
#pragma unroll
  for (int mt = 0; mt < 4; mt++) {
    long row = arow0 + wm * 128 + mt * 32 + m_lane;  // token
    long rb = row * STATE;
#pragma unroll
    for (int nt = 0; nt < 2; nt++) {
#pragma unroll
      for (int g = 0; g < 4; g++) {
        long col = brow0 + wn * 64 + nt * 32 + g * 8 + q4 * 4;  // interleaved col
        long ch = col >> 2;
        float kraw = acc[mt][nt][g * 4 + 0] * INV_SCALE;
        float uraw = acc[mt][nt][g * 4 + 1] * INV_SCALE;
        float gin  = acc[mt][nt][g * 4 + 2] * INV_SCALE;
        float gout = acc[mt][nt][g * 4 + 3] * INV_SCALE;
        float ah = sigmoidf_(kraw);                     // a-hat_t = sigma(K_t)
        float uu = uraw * sigmoidf_(gin) * (1.0f - ah); // u_t
        u16 pr[2];
        pr[0] = f2b(ah);  // low 16 bits
        pr[1] = f2b(uu);  // high 16 bits
        AU[rb + ch] = *(uint32_t*)pr;
        GO[rb + ch] = f2b(sigmoidf_(gout));
      }
    }
  }
}

// ---------------- GEMM2 MX-fp8: 128x128 block, BK=128 (R17, measured) --------
// 2-buffer 64 KB, 16 iterations; vrow = row*2 + khalf layout.
__device__ __forceinline__ void g2f8_stage(const u8* __restrict__ A,
                                           const u8* __restrict__ Bt,
                                           long arow0, long brow0, int k0,
                                           int wave, int lane, u8* As, u8* Bs) {
  const int K = STATE;
#pragma unroll
  for (int i = 0; i < 4; i++) {  // A: 1024 chunks (256 vrows x 4)
    int c = (wave * 4 + i) * 64 + lane;
    int vrow, kc; swz32_dec(c, vrow, kc);
    async_copy16(A + (arow0 + (vrow >> 1)) * K + k0 + (vrow & 1) * 64 + kc * 16,
                 (char*)As + (wave * 4 + i) * 1024);
  }
#pragma unroll
  for (int i = 0; i < 4; i++) {  // B: 1024 chunks (256 vrows x 4)
    int c = (wave * 4 + i) * 64 + lane;
    int vrow, kc; swz32_dec(c, vrow, kc);
    async_copy16(Bt + (brow0 + (vrow >> 1)) * K + k0 + (vrow & 1) * 64 + kc * 16,
                 (char*)Bs + (wave * 4 + i) * 1024);
  }
}

__global__ __launch_bounds__(256, 2) void gemm2_fp8(
    const u8* __restrict__ A, const u8* __restrict__ Bt,
    float* __restrict__ C, const float* __restrict__ resid) {
  __shared__ __align__(16) u8 As0[128 * 128], As1[128 * 128];  // 16 KB each
  __shared__ __align__(16) u8 Bs0[128 * 128], Bs1[128 * 128];  // 16 KB each -> 64 KB
  int tid = threadIdx.x;
  int lane = tid & 63, wave = tid >> 6;
  int wm = wave & 1, wn = wave >> 1;
  // T1: bijective XCD swizzle over the 512-block grid (row-major wg).
  int wg = xcd_swz(blockIdx.y * gridDim.x + blockIdx.x, gridDim.x * gridDim.y);
  int bx = wg & (gridDim.x - 1);          // gridDim.x = 8 (pow2)
  int by = wg >> 3;
  long arow0 = (long)by * 128;
  long brow0 = (long)bx * 128;
  int m_lane = lane & 31, q4 = lane >> 5;
  f32x16 acc[2][2] = {};

  g2f8_stage(A, Bt, arow0, brow0, 0, wave, lane, As0, Bs0);
  __syncthreads();  // cold fill, once

  for (int it = 0; it < 16; ++it) {
    const u8* Asc = (it & 1) ? As1 : As0;
    const u8* Bsc = (it & 1) ? Bs1 : Bs0;
    u8* Asn = (it & 1) ? As0 : As1;
    u8* Bsn = (it & 1) ? Bs0 : Bs1;
    if (it + 1 < 16)
      g2f8_stage(A, Bt, arow0, brow0, (it + 1) * 128, wave, lane, Asn, Bsn);
#pragma unroll
    for (int ks = 0; ks < 2; ks++) {  // two 64-k halves of the 128-k tile
      v8i af[2], bf[2];
#pragma unroll
      for (int mt = 0; mt < 2; mt++)
        af[mt] = ld_frag64(Asc, (wm * 64 + mt * 32 + m_lane) * 2 + ks, q4);
#pragma unroll
      for (int nt = 0; nt < 2; nt++)
        bf[nt] = ld_frag64(Bsc, (wn * 64 + nt * 32 + m_lane) * 2 + ks, q4);
#pragma unroll
      for (int mt = 0; mt < 2; mt++)
#pragma unroll
        for (int nt = 0; nt < 2; nt++)
          acc[mt][nt] = __builtin_amdgcn_mfma_scale_f32_32x32x64_f8f6f4(
              bf[nt], af[mt], acc[mt][nt], 0, 0, 0, 127, 0, 127);
    }
    __syncthreads();
  }
  // token = arow0 + wm*64 + mt*32 + m_lane; ycol = brow0 + wn*64 + nt*32 + g*8 + q4*4 + j
#pragma unroll
  for (int mt = 0; mt < 2; mt++) {
    long row = arow0 + wm * 64 + mt * 32 + m_lane;
#pragma unroll
    for (int nt = 0; nt < 2; nt++) {
#pragma unroll
      for (int g = 0; g < 4; g++) {
        long col = brow0 + wn * 64 + nt * 32 + g * 8 + q4 * 4;
        float4 rv = *(const float4*)(resid + row * DIMS + col);
        float4 ov;
        ov.x = acc[mt][nt][g * 4 + 0] * INV_SCALE + rv.x;
        ov.y = acc[mt][nt][g * 4 + 1] * INV_SCALE + rv.y;
        ov.z = acc[mt][nt][g * 4 + 2] * INV_SCALE + rv.z;
        ov.w = acc[mt][nt][g * 4 + 3] * INV_SCALE + rv.w;
        *(float4*)(C + row * DIMS + col) = ov;
      }
    }
  }
}

// ---------------- chunked gated linear scan (AU/GO inputs, R14 form) ---------
// AU[t][ch] = {a-hat_t = sigma(K_t), u_t} 2xbf16; GO[t][ch] = sigma(g_out) bf16.
// Recurrence: h_t = a_t h_{t-1} + u_t with a_t = a-hat_{t-1}, a_0 = 1.
// R20: carry_scan fusion REVERTED (R19 measured tail +37us: the per-block
// dependent-load recurrence chain cost far more than the launch it saved).
__global__ __launch_bounds__(256) void chunk_summary_kernel(
    const uint32_t* __restrict__ AU, float* __restrict__ carryA,
    float* __restrict__ carryU) {
  int b = blockIdx.x;
  int ch = blockIdx.y * 256 + threadIdx.x;
  int chunk = blockIdx.z;
  int t0 = chunk * CHUNKL;
  const uint32_t* base = AU + (long)b * SEQ * STATE + ch;
  // ap = a-hat_{t-1} entering token t; boundary from previous chunk's last token.
  float ap = 1.0f;
  if (chunk != 0) ap = b2f((u16)(base[(long)(t0 - 1) * STATE] & 0xffff));
  float A = 1.0f, U = 0.0f;
#pragma unroll 8
  for (int t = t0; t < t0 + CHUNKL; t++) {
    uint32_t w = base[(long)t * STATE];
    float ah = b2f((u16)(w & 0xffff));
    float u  = b2f((u16)(w >> 16));
    A *= ap;
    U = ap * U + u;
    ap = ah;
  }
  int cidx = (b * NCHUNK + chunk) * STATE + ch;
  carryA[cidx] = A;
  carryU[cidx] = U;
}

__global__ __launch_bounds__(256) void carry_scan_kernel(
    const float* __restrict__ carryA, const float* __restrict__ carryU,
    float* __restrict__ carryIn) {
  int idx = blockIdx.x * 256 + threadIdx.x;  // b*STATE + ch
  int b = idx >> 11;
  int ch = idx & 2047;
  float h = 0.0f;
#pragma unroll
  for (int c = 0; c < NCHUNK; c++) {
    int cidx = (b * NCHUNK + c) * STATE + ch;
    carryIn[cidx] = h;
    h = carryA[cidx] * h + carryU[cidx];
  }
}

// Pass C: local scan; writes h*sigma(g_out) as fp8*H_SCALE, PLAIN k-order
// (gemm2 is MX -- no kperm).
__global__ __launch_bounds__(256) void scan_chunk_kernel(
    const uint32_t* __restrict__ AU, const u16* __restrict__ GO,
    const float* __restrict__ carryIn, u8* __restrict__ sco8) {
  int b = blockIdx.x;
  int c0 = blockIdx.y * 32;
  int chunk = blockIdx.z;
  int tstart = chunk * CHUNKL;
  __shared__ float a_s[32][65], u_s[32][65], h_s[32][65];
  int tid = threadIdx.x;
  int lane = tid & 63, wave = tid >> 6;
  int cc = tid & 31;
  int tq = tid >> 5;

  float carryH[8], carryK[8];
#pragma unroll
  for (int i = 0; i < 8; i++) {
    int ch = c0 + wave * 8 + i;
    carryH[i] = carryIn[(b * NCHUNK + chunk) * STATE + ch];
    carryK[i] = (chunk == 0)
                    ? 1.0f
                    : b2f((u16)(AU[((long)(b * SEQ + tstart - 1)) * STATE + ch] & 0xffff));
  }

  float g_r[8];
  for (int t0 = tstart; t0 < tstart + CHUNKL; t0 += 64) {
#pragma unroll
    for (int i = 0; i < 8; i++) {
      int t = tq * 8 + i;
      long idx = ((long)(b * SEQ + t0 + t)) * STATE + c0 + cc;
      uint32_t w = AU[idx];
      a_s[cc][t] = b2f((u16)(w & 0xffff));  // a-hat_t
      u_s[cc][t] = b2f((u16)(w >> 16));     // u_t
      g_r[i] = b2f(GO[idx]);
    }
    __syncthreads();
#pragma unroll
    for (int i = 0; i < 8; i++) {
      int ch = wave * 8 + i;
      float aK = a_s[ch][lane];
      float u = u_s[ch][lane];
      float a = __shfl_up(aK, 1);   // a_t = a-hat_{t-1}
      if (lane == 0) a = carryK[i];
      float A = a, U = u;
#pragma unroll
      for (int d = 1; d < 64; d <<= 1) {
        float Au = __shfl_up(A, d);
        float Uu = __shfl_up(U, d);
        if (lane >= d) { U += A * Uu; A *= Au; }
      }
      float h = U + A * carryH[i];
      carryH[i] = __shfl(h, 63);
      carryK[i] = __shfl(aK, 63);
      h_s[ch][lane] = h;
    }
    __syncthreads();
#pragma unroll
    for (int i = 0; i < 8; i++) {
      int t = tq * 8 + i;
      sco8[((long)(b * SEQ + t0 + t)) * STATE + c0 + cc] =
          to_fp8(h_s[cc][t] * g_r[i] * H_SCALE);
    }
    __syncthreads();
  }
}

extern "C" void kernel_launch(void* const* d_in, const int* in_sizes, int n_in,
                              void* d_out, int out_size, void* d_ws, size_t ws_size,
                              hipStream_t stream) {
  const float* x    = (const float*)d_in[0];
  const float* ls   = (const float*)d_in[1];
  const float* rs   = (const float*)d_in[2];
  const float* ss   = (const float*)d_in[3];
  const float* Wk   = (const float*)d_in[4];
  const float* Wugg = (const float*)d_in[5];
  const float* Wout = (const float*)d_in[6];
  float* out = (float*)d_out;

  // workspace layout (~130 MB)
  char* ws = (char*)d_ws;
  u8*   W1f8 = (u8*)ws;                                  // [8192][1024] fp8 = 8 MB (interleaved)
  u8*   W2f8 = (u8*)(ws + 8388608);                      // [1024][2048] fp8 = 2 MB
  u8*   xn8  = (u8*)(ws + 10485760);                     // [8192][1024] fp8 = 8 MB
  uint32_t* AU = (uint32_t*)(ws + 18874368);             // [8192][2048] 2xbf16 = 64 MB
  u16*  GOb  = (u16*)(ws + 18874368 + 67108864);         // [8192][2048] bf16 = 32 MB
  u8*   sco8 = (u8*)(ws + 18874368 + 67108864 + 33554432); // [8192][2048] fp8 = 16.7 MB
  // carry buffers (3 x 512 KB) overlay xn8: xn8 is dead after gemm1.
  float* carryA  = (float*)xn8;
  float* carryU  = carryA + BATCH * NCHUNK * STATE;
  float* carryIn = carryU + BATCH * NCHUNK * STATE;

  // W1 -> fp8 (scaled, PLAIN k-order, channel-interleaved rows);
  // W2 -> fp8 (PLAIN k-order rows) -- both GEMMs are MX.
  transpose_fp8_kernel<<<dim3(STATE / 32, DIMS / 32), 256, 0, stream>>>(
      Wk, W1f8, DIMS, STATE, 0, 1, W1_SCALE);
  transpose_fp8_kernel<<<dim3(3 * STATE / 32, DIMS / 32), 256, 0, stream>>>(
      Wugg, W1f8, DIMS, 3 * STATE, 1, 1, W1_SCALE);
  transpose_fp8_kernel<<<dim3(DIMS / 32, STATE / 32), 256, 0, stream>>>(
      Wout, W2f8, STATE, DIMS, 0, 0, W2_SCALE);

  rmsnorm_kernel<<<TOKENS, 256, 0, stream>>>(x, ls, rs, ss, xn8);

  gemm1_fp8<<<dim3(N1 / 128, TOKENS / 256), 256, 0, stream>>>(xn8, W1f8, AU, GOb);

  chunk_summary_kernel<<<dim3(BATCH, STATE / 256, NCHUNK), 256, 0, stream>>>(
      AU, carryA, carryU);
  carry_scan_kernel<<<dim3(BATCH * STATE / 256), 256, 0, stream>>>(
      carryA, carryU, carryIn);
  scan_chunk_kernel<<<dim3(BATCH, STATE / 32, NCHUNK), 256, 0, stream>>>(
      AU, GOb, carryIn, sco8);

  gemm2_fp8<<<dim3(DIMS / 128, TOKENS / 128), 256, 0, stream>>>(
      sco8, W2f8, out, x);
}